// Round 17
// baseline (36.727 us; speedup 1.0000x reference)
//
#include <hip/hip_runtime.h>

#define NN 512
#define DD 128
#define HH 256

typedef unsigned int uint32;
typedef unsigned short u16;

__device__ __forceinline__ uint32 bfr(float f) {
    uint32 u = __float_as_uint(f);
    return (u + 0x7fffu + ((u >> 16) & 1u)) >> 16;   // RNE bf16
}

// ---------------------------------------------------------------------------
// k0: W1 -> W1T (f32); W2/Wo1/Wo2 -> transposed bf16. 64 blocks x 256 thr.
// (verbatim from R14/R16)
// ---------------------------------------------------------------------------
__global__ __launch_bounds__(256) void k0_tr(const float* __restrict__ W1,
                                             const float* __restrict__ W2,
                                             const float* __restrict__ Wo1,
                                             const float* __restrict__ Wo2,
                                             float* __restrict__ W1T,
                                             u16* __restrict__ wTb) {
    __shared__ float tl[64][68];
    const int b = blockIdx.x;
    const int t = threadIdx.x;
    const int m = b >> 4, tile = b & 15;
    const float* src = (m == 0) ? W1 : (m == 1) ? W2 : (m == 2) ? Wo1 : Wo2;
    const int sr0 = (tile >> 2) * 64;
    const int sc0 = (tile & 3) * 64;
    const int rr = t >> 4;
    const int cc = (t & 15) * 4;
    #pragma unroll
    for (int it = 0; it < 4; ++it) {
        const int row = rr + 16 * it;
        float4 v = *(const float4*)&src[(sr0 + row) * HH + sc0 + cc];
        tl[row][cc + 0] = v.x;
        tl[row][cc + 1] = v.y;
        tl[row][cc + 2] = v.z;
        tl[row][cc + 3] = v.w;
    }
    __syncthreads();
    if (m == 0) {
        #pragma unroll
        for (int it = 0; it < 4; ++it) {
            const int lc = rr + 16 * it;
            float4 o;
            o.x = tl[cc + 0][lc];
            o.y = tl[cc + 1][lc];
            o.z = tl[cc + 2][lc];
            o.w = tl[cc + 3][lc];
            *(float4*)&W1T[(sc0 + lc) * HH + sr0 + cc] = o;
        }
    } else {
        u16* dst = wTb + (m - 1) * (HH * HH);
        #pragma unroll
        for (int it = 0; it < 4; ++it) {
            const int lc = rr + 16 * it;
            uint32 lo = bfr(tl[cc + 0][lc]) | (bfr(tl[cc + 1][lc]) << 16);
            uint32 hi = bfr(tl[cc + 2][lc]) | (bfr(tl[cc + 3][lc]) << 16);
            uint32* p = (uint32*)&dst[(sc0 + lc) * HH + sr0 + cc];
            p[0] = lo;
            p[1] = hi;
        }
    }
}

// ---------------------------------------------------------------------------
// k1: pa(bf16) = x@Wa^T, pbb(f32) = x@Wb^T + b1 from W1T. 256 blk x 256 thr.
// (verbatim from R15/R16)
// ---------------------------------------------------------------------------
__global__ __launch_bounds__(256) void k1_papb(const float* __restrict__ x,
                                               const float* __restrict__ W1T,
                                               const float* __restrict__ b1,
                                               u16* __restrict__ pa_bf,
                                               float* __restrict__ pbb) {
    __shared__ float xs[2][DD];
    const int b = blockIdx.x;
    const int t = threadIdx.x;
    const int i0 = b * 2;
    if (t < 64) {
        const int f = t * 4;
        *(float4*)&xs[f >> 7][f & 127] = *(const float4*)&x[i0 * DD + f];
    }
    __syncthreads();
    const float* wt = W1T + t;
    const int crot = (b * 8) & 127;
    float pe0 = 0.f, po0 = 0.f, pe1 = 0.f, po1 = 0.f;
    float qe0 = 0.f, qo0 = 0.f, qe1 = 0.f, qo1 = 0.f;
    #pragma unroll 2
    for (int cc0 = 0; cc0 < 128; cc0 += 8) {
        const int c = (cc0 + crot) & 127;
        float w0 = wt[(c + 0) * HH], w1 = wt[(c + 1) * HH];
        float w2 = wt[(c + 2) * HH], w3 = wt[(c + 3) * HH];
        float w4 = wt[(c + 4) * HH], w5 = wt[(c + 5) * HH];
        float w6 = wt[(c + 6) * HH], w7 = wt[(c + 7) * HH];
        float v0 = wt[(128 + c + 0) * HH], v1 = wt[(128 + c + 1) * HH];
        float v2 = wt[(128 + c + 2) * HH], v3 = wt[(128 + c + 3) * HH];
        float v4 = wt[(128 + c + 4) * HH], v5 = wt[(128 + c + 5) * HH];
        float v6 = wt[(128 + c + 6) * HH], v7 = wt[(128 + c + 7) * HH];
        float4 x0a = *(const float4*)&xs[0][c];
        float4 x0b = *(const float4*)&xs[0][c + 4];
        float4 x1a = *(const float4*)&xs[1][c];
        float4 x1b = *(const float4*)&xs[1][c + 4];
        pe0 += w0 * x0a.x + w1 * x0a.y + w2 * x0a.z + w3 * x0a.w;
        po0 += w4 * x0b.x + w5 * x0b.y + w6 * x0b.z + w7 * x0b.w;
        pe1 += w0 * x1a.x + w1 * x1a.y + w2 * x1a.z + w3 * x1a.w;
        po1 += w4 * x1b.x + w5 * x1b.y + w6 * x1b.z + w7 * x1b.w;
        qe0 += v0 * x0a.x + v1 * x0a.y + v2 * x0a.z + v3 * x0a.w;
        qo0 += v4 * x0b.x + v5 * x0b.y + v6 * x0b.z + v7 * x0b.w;
        qe1 += v0 * x1a.x + v1 * x1a.y + v2 * x1a.z + v3 * x1a.w;
        qo1 += v4 * x1b.x + v5 * x1b.y + v6 * x1b.z + v7 * x1b.w;
    }
    const float bb = b1[t];
    pa_bf[i0 * HH + t] = (u16)bfr(pe0 + po0);
    pa_bf[(i0 + 1) * HH + t] = (u16)bfr(pe1 + po1);
    pbb[i0 * HH + t] = qe0 + qo0 + bb;
    pbb[(i0 + 1) * HH + t] = qe1 + qo1 + bb;
}

// ---------------------------------------------------------------------------
// k2: fused T + rowsum + 3 stages. 512 blocks x 512 threads, 1 row/block,
// ~14 KB LDS -> 2 blocks/CU co-resident (phase staggering hides barriers).
// ---------------------------------------------------------------------------
__global__ __launch_bounds__(512) void k2_rest(const float* __restrict__ adj,
                                               const u16* __restrict__ pa_bf,
                                               const float* __restrict__ pbb,
                                               const u16* __restrict__ wTb,
                                               const float* __restrict__ b2,
                                               const float* __restrict__ bo1,
                                               const float* __restrict__ bo2,
                                               float* __restrict__ out) {
    __shared__ float adjs[NN];            // 2 KB
    __shared__ float4 pbbs4[64];          // 1 KB
    __shared__ float ts[HH];              // 1 KB
    __shared__ float buf1[HH];            // 1 KB
    __shared__ float buf2[HH];            // 1 KB
    __shared__ float redbuf[2048];        // 8 KB
    __shared__ float rsum_s;

    const int b = blockIdx.x;             // row i
    const int t = threadIdx.x;

    if (t < 128) {
        *(float4*)&adjs[t * 4] = *(const float4*)&adj[b * NN + t * 4];
    } else if (t < 192) {
        pbbs4[t - 128] = *(const float4*)&pbb[b * HH + (t - 128) * 4];
    }
    __syncthreads();

    if (t < 64) {
        float s = 0.f;
        #pragma unroll
        for (int m = 0; m < 8; ++m) s += adjs[t + 64 * m];
        #pragma unroll
        for (int off = 32; off > 0; off >>= 1) s += __shfl_down(s, off, 64);
        if (t == 0) rsum_s = s;
    }

    // ---- T phase: hq = t&63 (4 h), js = t>>6 (8 groups x 64 j) ----
    {
        const int hq = t & 63;
        const int js = t >> 6;
        const float4 pb = pbbs4[hq];
        const uint32* paU = (const uint32*)pa_bf;   // [512][128] uints
        float4 ac = {0.f, 0.f, 0.f, 0.f};
        #pragma unroll 4
        for (int jj = 0; jj < 64; ++jj) {
            const int j = js * 64 + ((jj + b) & 63);
            uint2 w = *(const uint2*)&paU[j * 128 + hq * 2];
            float p0 = __uint_as_float(w.x << 16);
            float p1 = __uint_as_float(w.x & 0xffff0000u);
            float p2 = __uint_as_float(w.y << 16);
            float p3 = __uint_as_float(w.y & 0xffff0000u);
            const float a = adjs[j];
            ac.x += a * fmaxf(p0 + pb.x, 0.f);
            ac.y += a * fmaxf(p1 + pb.y, 0.f);
            ac.z += a * fmaxf(p2 + pb.z, 0.f);
            ac.w += a * fmaxf(p3 + pb.w, 0.f);
        }
        *(float4*)&redbuf[js * 256 + hq * 4] = ac;
        __syncthreads();
        if (t < 256) {
            float s = 0.f;
            #pragma unroll
            for (int q = 0; q < 8; ++q) s += redbuf[q * 256 + t];
            ts[t] = s;
        }
    }
    __syncthreads();

    const int kq = t & 63;
    const int hp = t >> 6;                 // 8 groups x 32 h
    const uint32* W2U  = (const uint32*)wTb;
    const uint32* Wo1U = W2U + (HH * HH) / 2;
    const uint32* Wo2U = W2U + (HH * HH);

    // stage 1: pred = (ts @ W2T + b2*rowsum)/N -> buf1
    {
        float4 a = {0.f, 0.f, 0.f, 0.f};
        #pragma unroll 4
        for (int hh = 0; hh < 32; ++hh) {
            const int h = hp * 32 + hh;
            uint32 wx = W2U[h * 128 + kq * 2];
            uint32 wy = W2U[h * 128 + kq * 2 + 1];
            float w0 = __uint_as_float(wx << 16);
            float w1 = __uint_as_float(wx & 0xffff0000u);
            float w2 = __uint_as_float(wy << 16);
            float w3 = __uint_as_float(wy & 0xffff0000u);
            const float v = ts[h];
            a.x += w0 * v; a.y += w1 * v; a.z += w2 * v; a.w += w3 * v;
        }
        *(float4*)&redbuf[hp * 256 + kq * 4] = a;
        __syncthreads();
        if (t < 256) {
            float s = 0.f;
            #pragma unroll
            for (int p = 0; p < 8; ++p) s += redbuf[p * 256 + t];
            buf1[t] = (s + b2[t] * rsum_s) * (1.0f / (float)NN);
        }
    }
    __syncthreads();

    // stage 2: h2 = relu(pred @ Wo1T + bo1) -> buf2
    {
        float4 a = {0.f, 0.f, 0.f, 0.f};
        #pragma unroll 4
        for (int hh = 0; hh < 32; ++hh) {
            const int h = hp * 32 + hh;
            uint32 wx = Wo1U[h * 128 + kq * 2];
            uint32 wy = Wo1U[h * 128 + kq * 2 + 1];
            float w0 = __uint_as_float(wx << 16);
            float w1 = __uint_as_float(wx & 0xffff0000u);
            float w2 = __uint_as_float(wy << 16);
            float w3 = __uint_as_float(wy & 0xffff0000u);
            const float v = buf1[h];
            a.x += w0 * v; a.y += w1 * v; a.z += w2 * v; a.w += w3 * v;
        }
        *(float4*)&redbuf[hp * 256 + kq * 4] = a;
        __syncthreads();
        if (t < 256) {
            float s = 0.f;
            #pragma unroll
            for (int p = 0; p < 8; ++p) s += redbuf[p * 256 + t];
            buf2[t] = fmaxf(s + bo1[t], 0.f);
        }
    }
    __syncthreads();

    // stage 3: out = h2 @ Wo2T + bo2
    {
        float4 a = {0.f, 0.f, 0.f, 0.f};
        #pragma unroll 4
        for (int hh = 0; hh < 32; ++hh) {
            const int h = hp * 32 + hh;
            uint32 wx = Wo2U[h * 128 + kq * 2];
            uint32 wy = Wo2U[h * 128 + kq * 2 + 1];
            float w0 = __uint_as_float(wx << 16);
            float w1 = __uint_as_float(wx & 0xffff0000u);
            float w2 = __uint_as_float(wy << 16);
            float w3 = __uint_as_float(wy & 0xffff0000u);
            const float v = buf2[h];
            a.x += w0 * v; a.y += w1 * v; a.z += w2 * v; a.w += w3 * v;
        }
        *(float4*)&redbuf[hp * 256 + kq * 4] = a;
        __syncthreads();
        if (t < 256) {
            float s = 0.f;
            #pragma unroll
            for (int p = 0; p < 8; ++p) s += redbuf[p * 256 + t];
            out[b * HH + t] = s + bo2[t];
        }
    }
}

extern "C" void kernel_launch(void* const* d_in, const int* in_sizes, int n_in,
                              void* d_out, int out_size, void* d_ws, size_t ws_size,
                              hipStream_t stream) {
    const float* x   = (const float*)d_in[0];
    const float* adj = (const float*)d_in[1];
    const float* W1  = (const float*)d_in[2];
    const float* b1  = (const float*)d_in[3];
    const float* W2  = (const float*)d_in[4];
    const float* b2  = (const float*)d_in[5];
    const float* Wo1 = (const float*)d_in[6];
    const float* bo1 = (const float*)d_in[7];
    const float* Wo2 = (const float*)d_in[8];
    const float* bo2 = (const float*)d_in[9];
    float* out = (float*)d_out;
    float* ws  = (float*)d_ws;

    // Disjoint float-slot regions (audited):
    //   W1T   : [0,       65536)   f32 256x256
    //   wTb   : [65536,  163840)   3 x 256x256 bf16 = 98304 float slots
    //   pa_bf : [163840, 229376)   512x256 bf16 = 65536 float slots
    //   pbb   : [229376, 360448)   f32 512x256
    float* W1T   = ws;
    u16*   wTb   = (u16*)(ws + 65536);
    u16*   pa_bf = (u16*)(ws + 163840);
    float* pbb   = ws + 229376;

    k0_tr<<<64, 256, 0, stream>>>(W1, W2, Wo1, Wo2, W1T, wTb);
    k1_papb<<<256, 256, 0, stream>>>(x, W1T, b1, pa_bf, pbb);
    k2_rest<<<512, 512, 0, stream>>>(adj, pa_bf, pbb, wTb, b2, bo1, bo2, out);
}

// Round 18
// 33.955 us; speedup vs baseline: 1.0816x; 1.0816x over previous
//
#include <hip/hip_runtime.h>

#define NN 512
#define DD 128
#define HH 256

typedef unsigned int uint32;
typedef unsigned short u16;

__device__ __forceinline__ float dot4(float4 a, float4 b) {
    return a.x * b.x + a.y * b.y + a.z * b.z + a.w * b.w;
}

__device__ __forceinline__ uint32 bfr(float f) {
    uint32 u = __float_as_uint(f);
    return (u + 0x7fffu + ((u >> 16) & 1u)) >> 16;   // RNE bf16
}

// ---------------------------------------------------------------------------
// kA: blocks 0..255  : pa/pbb (direct W1 row gather; L1 serves 3/4 of each
//                      row's line reuse). Verbatim R10 structure.
//     blocks 256..303: transpose W2/Wo1/Wo2 -> bf16 wTb (R14 k0 branch).
// ---------------------------------------------------------------------------
__global__ __launch_bounds__(256) void kA(const float* __restrict__ x,
                                          const float* __restrict__ W1,
                                          const float* __restrict__ b1,
                                          const float* __restrict__ W2,
                                          const float* __restrict__ Wo1,
                                          const float* __restrict__ Wo2,
                                          float* __restrict__ pa,
                                          float* __restrict__ pbb,
                                          u16* __restrict__ wTb) {
    __shared__ float smem[64 * 68];
    const int b = blockIdx.x;
    const int t = threadIdx.x;
    if (b < 256) {
        float (*xs)[DD] = (float(*)[DD])smem;
        const int i0 = b * 2;
        if (t < 64) {
            const int f = t * 4;
            *(float4*)&xs[f >> 7][f & 127] = *(const float4*)&x[i0 * DD + f];
        }
        __syncthreads();
        const int h = t;
        const float4* w4 = (const float4*)(W1 + h * (2 * DD));
        const float4* x0 = (const float4*)&xs[0][0];
        const float4* x1 = (const float4*)&xs[1][0];
        float a0 = 0.f, a1 = 0.f, c0 = 0.f, c1 = 0.f;
        #pragma unroll 8
        for (int d4 = 0; d4 < DD / 4; ++d4) {
            float4 wa = w4[d4];
            float4 wb = w4[d4 + 32];
            float4 v0 = x0[d4];
            float4 v1 = x1[d4];
            a0 += dot4(wa, v0);
            a1 += dot4(wa, v1);
            c0 += dot4(wb, v0);
            c1 += dot4(wb, v1);
        }
        const float bb = b1[h];
        pa[i0 * HH + h] = a0;
        pa[(i0 + 1) * HH + h] = a1;
        pbb[i0 * HH + h] = c0 + bb;
        pbb[(i0 + 1) * HH + h] = c1 + bb;
    } else {
        float (*tl)[68] = (float(*)[68])smem;
        const int bb = b - 256;
        const int m = bb >> 4, tile = bb & 15;
        const float* src = (m == 0) ? W2 : (m == 1) ? Wo1 : Wo2;
        u16* dst = wTb + m * (HH * HH);
        const int sr0 = (tile >> 2) * 64;
        const int sc0 = (tile & 3) * 64;
        const int rr = t >> 4;
        const int cc = (t & 15) * 4;
        #pragma unroll
        for (int it = 0; it < 4; ++it) {
            const int row = rr + 16 * it;
            float4 v = *(const float4*)&src[(sr0 + row) * HH + sc0 + cc];
            tl[row][cc + 0] = v.x;
            tl[row][cc + 1] = v.y;
            tl[row][cc + 2] = v.z;
            tl[row][cc + 3] = v.w;
        }
        __syncthreads();
        #pragma unroll
        for (int it = 0; it < 4; ++it) {
            const int lc = rr + 16 * it;
            uint32 lo = bfr(tl[cc + 0][lc]) | (bfr(tl[cc + 1][lc]) << 16);
            uint32 hi = bfr(tl[cc + 2][lc]) | (bfr(tl[cc + 3][lc]) << 16);
            uint32* p = (uint32*)&dst[(sc0 + lc) * HH + sr0 + cc];
            p[0] = lo;
            p[1] = hi;
        }
    }
}

// ---------------------------------------------------------------------------
// k2: fused T + rowsum + 3 stage GEMMs (R14 best-measured, verbatim).
// f32 pa float4 T-phase, bf16 stage weights. 256 blocks x 1024 threads.
// ---------------------------------------------------------------------------
__global__ __launch_bounds__(1024) void k2_rest(const float* __restrict__ adj,
                                                const float* __restrict__ pa,
                                                const float* __restrict__ pbb,
                                                const u16* __restrict__ wTb,
                                                const float* __restrict__ b2,
                                                const float* __restrict__ bo1,
                                                const float* __restrict__ bo2,
                                                float* __restrict__ out) {
    __shared__ float adjs[2][NN];
    __shared__ float4 pbbs4[2][64];
    __shared__ float ts[2][HH];
    __shared__ float buf1[2][HH];
    __shared__ float buf2[2][HH];
    __shared__ float redbuf[8192];
    __shared__ float rsum_s[2];

    const int b = blockIdx.x;
    const int t = threadIdx.x;
    const int i0 = b * 2;

    if (t < 256) {
        const int f = t * 4;
        *(float4*)&adjs[f >> 9][f & 511] = *(const float4*)&adj[(i0 + (f >> 9)) * NN + (f & 511)];
    } else if (t < 384) {
        const int u = t - 256;
        const int r = u >> 6, q = u & 63;
        pbbs4[r][q] = *(const float4*)&pbb[(i0 + r) * HH + q * 4];
    }
    __syncthreads();

    if (t < 128) {
        const int r = t >> 6, l = t & 63;
        float s = 0.f;
        #pragma unroll
        for (int m = 0; m < 8; ++m) s += adjs[r][l + 64 * m];
        #pragma unroll
        for (int off = 32; off > 0; off >>= 1) s += __shfl_down(s, off, 64);
        if (l == 0) rsum_s[r] = s;
    }

    // ---- T phase: hq = t&63 (h-quad), js = t>>6 (16-way j split) ----
    {
        const int hq = t & 63;
        const int js = t >> 6;
        const float4 pb0 = pbbs4[0][hq];
        const float4 pb1 = pbbs4[1][hq];
        float4 ac0 = {0.f, 0.f, 0.f, 0.f};
        float4 ac1 = {0.f, 0.f, 0.f, 0.f};
        #pragma unroll 4
        for (int jj = 0; jj < 32; ++jj) {
            const int j = js * 32 + ((jj + b) & 31);
            float4 p = *(const float4*)&pa[j * HH + hq * 4];
            const float a0 = adjs[0][j];
            const float a1 = adjs[1][j];
            ac0.x += a0 * fmaxf(p.x + pb0.x, 0.f);
            ac0.y += a0 * fmaxf(p.y + pb0.y, 0.f);
            ac0.z += a0 * fmaxf(p.z + pb0.z, 0.f);
            ac0.w += a0 * fmaxf(p.w + pb0.w, 0.f);
            ac1.x += a1 * fmaxf(p.x + pb1.x, 0.f);
            ac1.y += a1 * fmaxf(p.y + pb1.y, 0.f);
            ac1.z += a1 * fmaxf(p.z + pb1.z, 0.f);
            ac1.w += a1 * fmaxf(p.w + pb1.w, 0.f);
        }
        *(float4*)&redbuf[(js * 2 + 0) * 256 + hq * 4] = ac0;
        *(float4*)&redbuf[(js * 2 + 1) * 256 + hq * 4] = ac1;
        __syncthreads();
        if (t < 512) {
            const int r = t >> 8, h = t & 255;
            float s = 0.f;
            #pragma unroll
            for (int q = 0; q < 16; ++q) s += redbuf[(q * 2 + r) * 256 + h];
            ts[r][h] = s;
        }
    }
    __syncthreads();

    const int kq = t & 63;
    const int hp = t >> 6;
    const uint32* W2U  = (const uint32*)wTb;
    const uint32* Wo1U = W2U + (HH * HH) / 2;
    const uint32* Wo2U = W2U + (HH * HH);

    // stage 1: pred = (ts @ W2T + b2*rowsum)/N -> buf1
    {
        float4 a0 = {0.f, 0.f, 0.f, 0.f};
        float4 a1 = {0.f, 0.f, 0.f, 0.f};
        #pragma unroll 4
        for (int hh = 0; hh < 16; ++hh) {
            const int h = hp * 16 + hh;
            uint32 wx = W2U[h * 128 + kq * 2];
            uint32 wy = W2U[h * 128 + kq * 2 + 1];
            float w0 = __uint_as_float(wx << 16);
            float w1 = __uint_as_float(wx & 0xffff0000u);
            float w2 = __uint_as_float(wy << 16);
            float w3 = __uint_as_float(wy & 0xffff0000u);
            const float v0 = ts[0][h];
            const float v1 = ts[1][h];
            a0.x += w0 * v0; a0.y += w1 * v0; a0.z += w2 * v0; a0.w += w3 * v0;
            a1.x += w0 * v1; a1.y += w1 * v1; a1.z += w2 * v1; a1.w += w3 * v1;
        }
        *(float4*)&redbuf[(hp * 2 + 0) * 256 + kq * 4] = a0;
        *(float4*)&redbuf[(hp * 2 + 1) * 256 + kq * 4] = a1;
        __syncthreads();
        if (t < 512) {
            const int r = t >> 8, k = t & 255;
            float s = 0.f;
            #pragma unroll
            for (int p = 0; p < 16; ++p) s += redbuf[(p * 2 + r) * 256 + k];
            buf1[r][k] = (s + b2[k] * rsum_s[r]) * (1.0f / (float)NN);
        }
    }
    __syncthreads();

    // stage 2: h2 = relu(pred @ Wo1T + bo1) -> buf2
    {
        float4 a0 = {0.f, 0.f, 0.f, 0.f};
        float4 a1 = {0.f, 0.f, 0.f, 0.f};
        #pragma unroll 4
        for (int hh = 0; hh < 16; ++hh) {
            const int h = hp * 16 + hh;
            uint32 wx = Wo1U[h * 128 + kq * 2];
            uint32 wy = Wo1U[h * 128 + kq * 2 + 1];
            float w0 = __uint_as_float(wx << 16);
            float w1 = __uint_as_float(wx & 0xffff0000u);
            float w2 = __uint_as_float(wy << 16);
            float w3 = __uint_as_float(wy & 0xffff0000u);
            const float v0 = buf1[0][h];
            const float v1 = buf1[1][h];
            a0.x += w0 * v0; a0.y += w1 * v0; a0.z += w2 * v0; a0.w += w3 * v0;
            a1.x += w0 * v1; a1.y += w1 * v1; a1.z += w2 * v1; a1.w += w3 * v1;
        }
        *(float4*)&redbuf[(hp * 2 + 0) * 256 + kq * 4] = a0;
        *(float4*)&redbuf[(hp * 2 + 1) * 256 + kq * 4] = a1;
        __syncthreads();
        if (t < 512) {
            const int r = t >> 8, k = t & 255;
            float s = 0.f;
            #pragma unroll
            for (int p = 0; p < 16; ++p) s += redbuf[(p * 2 + r) * 256 + k];
            buf2[r][k] = fmaxf(s + bo1[k], 0.f);
        }
    }
    __syncthreads();

    // stage 3: out = h2 @ Wo2T + bo2
    {
        float4 a0 = {0.f, 0.f, 0.f, 0.f};
        float4 a1 = {0.f, 0.f, 0.f, 0.f};
        #pragma unroll 4
        for (int hh = 0; hh < 16; ++hh) {
            const int h = hp * 16 + hh;
            uint32 wx = Wo2U[h * 128 + kq * 2];
            uint32 wy = Wo2U[h * 128 + kq * 2 + 1];
            float w0 = __uint_as_float(wx << 16);
            float w1 = __uint_as_float(wx & 0xffff0000u);
            float w2 = __uint_as_float(wy << 16);
            float w3 = __uint_as_float(wy & 0xffff0000u);
            const float v0 = buf2[0][h];
            const float v1 = buf2[1][h];
            a0.x += w0 * v0; a0.y += w1 * v0; a0.z += w2 * v0; a0.w += w3 * v0;
            a1.x += w0 * v1; a1.y += w1 * v1; a1.z += w2 * v1; a1.w += w3 * v1;
        }
        *(float4*)&redbuf[(hp * 2 + 0) * 256 + kq * 4] = a0;
        *(float4*)&redbuf[(hp * 2 + 1) * 256 + kq * 4] = a1;
        __syncthreads();
        if (t < 512) {
            const int r = t >> 8, k = t & 255;
            float s = 0.f;
            #pragma unroll
            for (int p = 0; p < 16; ++p) s += redbuf[(p * 2 + r) * 256 + k];
            out[(i0 + r) * HH + k] = s + bo2[k];
        }
    }
}

extern "C" void kernel_launch(void* const* d_in, const int* in_sizes, int n_in,
                              void* d_out, int out_size, void* d_ws, size_t ws_size,
                              hipStream_t stream) {
    const float* x   = (const float*)d_in[0];
    const float* adj = (const float*)d_in[1];
    const float* W1  = (const float*)d_in[2];
    const float* b1  = (const float*)d_in[3];
    const float* W2  = (const float*)d_in[4];
    const float* b2  = (const float*)d_in[5];
    const float* Wo1 = (const float*)d_in[6];
    const float* bo1 = (const float*)d_in[7];
    const float* Wo2 = (const float*)d_in[8];
    const float* bo2 = (const float*)d_in[9];
    float* out = (float*)d_out;
    float* ws  = (float*)d_ws;

    // Disjoint float-slot regions (audited):
    //   wTb : [0,       98304)   3 x 256x256 bf16 = 98304 float slots
    //   pa  : [98304,  229376)   f32 512x256
    //   pbb : [229376, 360448)   f32 512x256
    u16*   wTb = (u16*)ws;
    float* pa  = ws + 98304;
    float* pbb = ws + 229376;

    kA<<<304, 256, 0, stream>>>(x, W1, b1, W2, Wo1, Wo2, pa, pbb, wTb);
    k2_rest<<<256, 1024, 0, stream>>>(adj, pa, pbb, wTb, b2, bo1, bo2, out);
}

// Round 19
// 32.310 us; speedup vs baseline: 1.1367x; 1.0509x over previous
//
#include <hip/hip_runtime.h>

#define NN 512
#define DD 128
#define HH 256

typedef unsigned int uint32;
typedef unsigned short u16;

__device__ __forceinline__ uint32 bfr(float f) {
    uint32 u = __float_as_uint(f);
    return (u + 0x7fffu + ((u >> 16) & 1u)) >> 16;   // RNE bf16
}

// ---------------------------------------------------------------------------
// k0: W1 -> W1T (f32); W2/Wo1/Wo2 -> transposed bf16. 64 blocks x 256 thr.
// (verbatim from R14)
// ---------------------------------------------------------------------------
__global__ __launch_bounds__(256) void k0_tr(const float* __restrict__ W1,
                                             const float* __restrict__ W2,
                                             const float* __restrict__ Wo1,
                                             const float* __restrict__ Wo2,
                                             float* __restrict__ W1T,
                                             u16* __restrict__ wTb) {
    __shared__ float tl[64][68];
    const int b = blockIdx.x;
    const int t = threadIdx.x;
    const int m = b >> 4, tile = b & 15;
    const float* src = (m == 0) ? W1 : (m == 1) ? W2 : (m == 2) ? Wo1 : Wo2;
    const int sr0 = (tile >> 2) * 64;
    const int sc0 = (tile & 3) * 64;
    const int rr = t >> 4;
    const int cc = (t & 15) * 4;
    #pragma unroll
    for (int it = 0; it < 4; ++it) {
        const int row = rr + 16 * it;
        float4 v = *(const float4*)&src[(sr0 + row) * HH + sc0 + cc];
        tl[row][cc + 0] = v.x;
        tl[row][cc + 1] = v.y;
        tl[row][cc + 2] = v.z;
        tl[row][cc + 3] = v.w;
    }
    __syncthreads();
    if (m == 0) {
        #pragma unroll
        for (int it = 0; it < 4; ++it) {
            const int lc = rr + 16 * it;
            float4 o;
            o.x = tl[cc + 0][lc];
            o.y = tl[cc + 1][lc];
            o.z = tl[cc + 2][lc];
            o.w = tl[cc + 3][lc];
            *(float4*)&W1T[(sc0 + lc) * HH + sr0 + cc] = o;
        }
    } else {
        u16* dst = wTb + (m - 1) * (HH * HH);
        #pragma unroll
        for (int it = 0; it < 4; ++it) {
            const int lc = rr + 16 * it;
            uint32 lo = bfr(tl[cc + 0][lc]) | (bfr(tl[cc + 1][lc]) << 16);
            uint32 hi = bfr(tl[cc + 2][lc]) | (bfr(tl[cc + 3][lc]) << 16);
            uint32* p = (uint32*)&dst[(sc0 + lc) * HH + sr0 + cc];
            p[0] = lo;
            p[1] = hi;
        }
    }
}

// ---------------------------------------------------------------------------
// k1: pa(f32) = x@Wa^T, pbb(f32) = x@Wb^T + b1 from W1T. 256 blk x 256 thr.
// (verbatim from R14)
// ---------------------------------------------------------------------------
__global__ __launch_bounds__(256) void k1_papb(const float* __restrict__ x,
                                               const float* __restrict__ W1T,
                                               const float* __restrict__ b1,
                                               float* __restrict__ pa,
                                               float* __restrict__ pbb) {
    __shared__ float xs[2][DD];
    const int b = blockIdx.x;
    const int t = threadIdx.x;
    const int i0 = b * 2;
    if (t < 64) {
        const int f = t * 4;
        *(float4*)&xs[f >> 7][f & 127] = *(const float4*)&x[i0 * DD + f];
    }
    __syncthreads();
    const float* wt = W1T + t;
    const int crot = (b * 8) & 127;
    float pe0 = 0.f, po0 = 0.f, pe1 = 0.f, po1 = 0.f;
    float qe0 = 0.f, qo0 = 0.f, qe1 = 0.f, qo1 = 0.f;
    #pragma unroll 2
    for (int cc0 = 0; cc0 < 128; cc0 += 8) {
        const int c = (cc0 + crot) & 127;
        float w0 = wt[(c + 0) * HH], w1 = wt[(c + 1) * HH];
        float w2 = wt[(c + 2) * HH], w3 = wt[(c + 3) * HH];
        float w4 = wt[(c + 4) * HH], w5 = wt[(c + 5) * HH];
        float w6 = wt[(c + 6) * HH], w7 = wt[(c + 7) * HH];
        float v0 = wt[(128 + c + 0) * HH], v1 = wt[(128 + c + 1) * HH];
        float v2 = wt[(128 + c + 2) * HH], v3 = wt[(128 + c + 3) * HH];
        float v4 = wt[(128 + c + 4) * HH], v5 = wt[(128 + c + 5) * HH];
        float v6 = wt[(128 + c + 6) * HH], v7 = wt[(128 + c + 7) * HH];
        float4 x0a = *(const float4*)&xs[0][c];
        float4 x0b = *(const float4*)&xs[0][c + 4];
        float4 x1a = *(const float4*)&xs[1][c];
        float4 x1b = *(const float4*)&xs[1][c + 4];
        pe0 += w0 * x0a.x + w1 * x0a.y + w2 * x0a.z + w3 * x0a.w;
        po0 += w4 * x0b.x + w5 * x0b.y + w6 * x0b.z + w7 * x0b.w;
        pe1 += w0 * x1a.x + w1 * x1a.y + w2 * x1a.z + w3 * x1a.w;
        po1 += w4 * x1b.x + w5 * x1b.y + w6 * x1b.z + w7 * x1b.w;
        qe0 += v0 * x0a.x + v1 * x0a.y + v2 * x0a.z + v3 * x0a.w;
        qo0 += v4 * x0b.x + v5 * x0b.y + v6 * x0b.z + v7 * x0b.w;
        qe1 += v0 * x1a.x + v1 * x1a.y + v2 * x1a.z + v3 * x1a.w;
        qo1 += v4 * x1b.x + v5 * x1b.y + v6 * x1b.z + v7 * x1b.w;
    }
    const float bb = b1[t];
    pa[i0 * HH + t] = pe0 + po0;
    pa[(i0 + 1) * HH + t] = pe1 + po1;
    pbb[i0 * HH + t] = qe0 + qo0 + bb;
    pbb[(i0 + 1) * HH + t] = qe1 + qo1 + bb;
}

// ---------------------------------------------------------------------------
// k2: R14 fused structure + cross-phase weight register prefetch.
// Stage-1 weights load at kernel entry (hidden under staging + T phase);
// stage-N+1 weights load right after stage-N's FMA loop (hidden under
// redbuf write + barrier + reduce). 256 blocks x 1024 threads.
// ---------------------------------------------------------------------------
__global__ __launch_bounds__(1024) void k2_rest(const float* __restrict__ adj,
                                                const float* __restrict__ pa,
                                                const float* __restrict__ pbb,
                                                const u16* __restrict__ wTb,
                                                const float* __restrict__ b2,
                                                const float* __restrict__ bo1,
                                                const float* __restrict__ bo2,
                                                float* __restrict__ out) {
    __shared__ float adjs[2][NN];
    __shared__ float4 pbbs4[2][64];
    __shared__ float ts[2][HH];
    __shared__ float buf1[2][HH];
    __shared__ float buf2[2][HH];
    __shared__ float redbuf[8192];
    __shared__ float rsum_s[2];

    const int b = blockIdx.x;
    const int t = threadIdx.x;
    const int i0 = b * 2;

    const int kq = t & 63;
    const int hp = t >> 6;
    const uint32* W2U  = (const uint32*)wTb;
    const uint32* Wo1U = W2U + (HH * HH) / 2;
    const uint32* Wo2U = W2U + (HH * HH);

    // ---- prefetch stage-1 weights NOW: in flight under staging + T phase ----
    uint2 wpre[16];
    #pragma unroll
    for (int hh = 0; hh < 16; ++hh)
        wpre[hh] = *(const uint2*)&W2U[(hp * 16 + hh) * 128 + kq * 2];

    if (t < 256) {
        const int f = t * 4;
        *(float4*)&adjs[f >> 9][f & 511] = *(const float4*)&adj[(i0 + (f >> 9)) * NN + (f & 511)];
    } else if (t < 384) {
        const int u = t - 256;
        const int r = u >> 6, q = u & 63;
        pbbs4[r][q] = *(const float4*)&pbb[(i0 + r) * HH + q * 4];
    }
    __syncthreads();

    if (t < 128) {
        const int r = t >> 6, l = t & 63;
        float s = 0.f;
        #pragma unroll
        for (int m = 0; m < 8; ++m) s += adjs[r][l + 64 * m];
        #pragma unroll
        for (int off = 32; off > 0; off >>= 1) s += __shfl_down(s, off, 64);
        if (l == 0) rsum_s[r] = s;
    }

    // ---- T phase: hq = t&63 (h-quad), js = t>>6 (16-way j split) ----
    {
        const int hq = t & 63;
        const int js = t >> 6;
        const float4 pb0 = pbbs4[0][hq];
        const float4 pb1 = pbbs4[1][hq];
        float4 ac0 = {0.f, 0.f, 0.f, 0.f};
        float4 ac1 = {0.f, 0.f, 0.f, 0.f};
        #pragma unroll 4
        for (int jj = 0; jj < 32; ++jj) {
            const int j = js * 32 + ((jj + b) & 31);
            float4 p = *(const float4*)&pa[j * HH + hq * 4];
            const float a0 = adjs[0][j];
            const float a1 = adjs[1][j];
            ac0.x += a0 * fmaxf(p.x + pb0.x, 0.f);
            ac0.y += a0 * fmaxf(p.y + pb0.y, 0.f);
            ac0.z += a0 * fmaxf(p.z + pb0.z, 0.f);
            ac0.w += a0 * fmaxf(p.w + pb0.w, 0.f);
            ac1.x += a1 * fmaxf(p.x + pb1.x, 0.f);
            ac1.y += a1 * fmaxf(p.y + pb1.y, 0.f);
            ac1.z += a1 * fmaxf(p.z + pb1.z, 0.f);
            ac1.w += a1 * fmaxf(p.w + pb1.w, 0.f);
        }
        *(float4*)&redbuf[(js * 2 + 0) * 256 + hq * 4] = ac0;
        *(float4*)&redbuf[(js * 2 + 1) * 256 + hq * 4] = ac1;
        __syncthreads();
        if (t < 512) {
            const int r = t >> 8, h = t & 255;
            float s = 0.f;
            #pragma unroll
            for (int q = 0; q < 16; ++q) s += redbuf[(q * 2 + r) * 256 + h];
            ts[r][h] = s;
        }
    }
    __syncthreads();

    // stage 1: pred = (ts @ W2T + b2*rowsum)/N -> buf1   [uses prefetched wpre]
    {
        float4 a0 = {0.f, 0.f, 0.f, 0.f};
        float4 a1 = {0.f, 0.f, 0.f, 0.f};
        #pragma unroll
        for (int hh = 0; hh < 16; ++hh) {
            const int h = hp * 16 + hh;
            uint32 wx = wpre[hh].x;
            uint32 wy = wpre[hh].y;
            float w0 = __uint_as_float(wx << 16);
            float w1 = __uint_as_float(wx & 0xffff0000u);
            float w2 = __uint_as_float(wy << 16);
            float w3 = __uint_as_float(wy & 0xffff0000u);
            const float v0 = ts[0][h];
            const float v1 = ts[1][h];
            a0.x += w0 * v0; a0.y += w1 * v0; a0.z += w2 * v0; a0.w += w3 * v0;
            a1.x += w0 * v1; a1.y += w1 * v1; a1.z += w2 * v1; a1.w += w3 * v1;
        }
        // issue stage-2 prefetch: hides under redbuf write + barrier + reduce
        #pragma unroll
        for (int hh = 0; hh < 16; ++hh)
            wpre[hh] = *(const uint2*)&Wo1U[(hp * 16 + hh) * 128 + kq * 2];
        *(float4*)&redbuf[(hp * 2 + 0) * 256 + kq * 4] = a0;
        *(float4*)&redbuf[(hp * 2 + 1) * 256 + kq * 4] = a1;
        __syncthreads();
        if (t < 512) {
            const int r = t >> 8, k = t & 255;
            float s = 0.f;
            #pragma unroll
            for (int p = 0; p < 16; ++p) s += redbuf[(p * 2 + r) * 256 + k];
            buf1[r][k] = (s + b2[k] * rsum_s[r]) * (1.0f / (float)NN);
        }
    }
    __syncthreads();

    // stage 2: h2 = relu(pred @ Wo1T + bo1) -> buf2   [uses prefetched wpre]
    {
        float4 a0 = {0.f, 0.f, 0.f, 0.f};
        float4 a1 = {0.f, 0.f, 0.f, 0.f};
        #pragma unroll
        for (int hh = 0; hh < 16; ++hh) {
            const int h = hp * 16 + hh;
            uint32 wx = wpre[hh].x;
            uint32 wy = wpre[hh].y;
            float w0 = __uint_as_float(wx << 16);
            float w1 = __uint_as_float(wx & 0xffff0000u);
            float w2 = __uint_as_float(wy << 16);
            float w3 = __uint_as_float(wy & 0xffff0000u);
            const float v0 = buf1[0][h];
            const float v1 = buf1[1][h];
            a0.x += w0 * v0; a0.y += w1 * v0; a0.z += w2 * v0; a0.w += w3 * v0;
            a1.x += w0 * v1; a1.y += w1 * v1; a1.z += w2 * v1; a1.w += w3 * v1;
        }
        // issue stage-3 prefetch
        #pragma unroll
        for (int hh = 0; hh < 16; ++hh)
            wpre[hh] = *(const uint2*)&Wo2U[(hp * 16 + hh) * 128 + kq * 2];
        *(float4*)&redbuf[(hp * 2 + 0) * 256 + kq * 4] = a0;
        *(float4*)&redbuf[(hp * 2 + 1) * 256 + kq * 4] = a1;
        __syncthreads();
        if (t < 512) {
            const int r = t >> 8, k = t & 255;
            float s = 0.f;
            #pragma unroll
            for (int p = 0; p < 16; ++p) s += redbuf[(p * 2 + r) * 256 + k];
            buf2[r][k] = fmaxf(s + bo1[k], 0.f);
        }
    }
    __syncthreads();

    // stage 3: out = h2 @ Wo2T + bo2   [uses prefetched wpre]
    {
        float4 a0 = {0.f, 0.f, 0.f, 0.f};
        float4 a1 = {0.f, 0.f, 0.f, 0.f};
        #pragma unroll
        for (int hh = 0; hh < 16; ++hh) {
            const int h = hp * 16 + hh;
            uint32 wx = wpre[hh].x;
            uint32 wy = wpre[hh].y;
            float w0 = __uint_as_float(wx << 16);
            float w1 = __uint_as_float(wx & 0xffff0000u);
            float w2 = __uint_as_float(wy << 16);
            float w3 = __uint_as_float(wy & 0xffff0000u);
            const float v0 = buf2[0][h];
            const float v1 = buf2[1][h];
            a0.x += w0 * v0; a0.y += w1 * v0; a0.z += w2 * v0; a0.w += w3 * v0;
            a1.x += w0 * v1; a1.y += w1 * v1; a1.z += w2 * v1; a1.w += w3 * v1;
        }
        *(float4*)&redbuf[(hp * 2 + 0) * 256 + kq * 4] = a0;
        *(float4*)&redbuf[(hp * 2 + 1) * 256 + kq * 4] = a1;
        __syncthreads();
        if (t < 512) {
            const int r = t >> 8, k = t & 255;
            float s = 0.f;
            #pragma unroll
            for (int p = 0; p < 16; ++p) s += redbuf[(p * 2 + r) * 256 + k];
            out[(i0 + r) * HH + k] = s + bo2[k];
        }
    }
}

extern "C" void kernel_launch(void* const* d_in, const int* in_sizes, int n_in,
                              void* d_out, int out_size, void* d_ws, size_t ws_size,
                              hipStream_t stream) {
    const float* x   = (const float*)d_in[0];
    const float* adj = (const float*)d_in[1];
    const float* W1  = (const float*)d_in[2];
    const float* b1  = (const float*)d_in[3];
    const float* W2  = (const float*)d_in[4];
    const float* b2  = (const float*)d_in[5];
    const float* Wo1 = (const float*)d_in[6];
    const float* bo1 = (const float*)d_in[7];
    const float* Wo2 = (const float*)d_in[8];
    const float* bo2 = (const float*)d_in[9];
    float* out = (float*)d_out;
    float* ws  = (float*)d_ws;

    // Disjoint float-slot regions (audited):
    //   W1T : [0,       65536)   f32 256x256
    //   wTb : [65536,  163840)   3 x 256x256 bf16 = 98304 float slots
    //   pa  : [163840, 294912)   f32 512x256
    //   pbb : [294912, 425984)   f32 512x256
    float* W1T = ws;
    u16*   wTb = (u16*)(ws + 65536);
    float* pa  = ws + 163840;
    float* pbb = ws + 294912;

    k0_tr<<<64, 256, 0, stream>>>(W1, W2, Wo1, Wo2, W1T, wTb);
    k1_papb<<<256, 256, 0, stream>>>(x, W1T, b1, pa, pbb);
    k2_rest<<<256, 1024, 0, stream>>>(adj, pa, pbb, wTb, b2, bo1, bo2, out);
}

// Round 20
// 31.194 us; speedup vs baseline: 1.1774x; 1.0358x over previous
//
#include <hip/hip_runtime.h>

#define NN 512
#define DD 128
#define HH 256

typedef unsigned int uint32;
typedef unsigned short u16;

__device__ __forceinline__ uint32 bfr(float f) {
    uint32 u = __float_as_uint(f);
    return (u + 0x7fffu + ((u >> 16) & 1u)) >> 16;   // RNE bf16
}

// ---------------------------------------------------------------------------
// k0: W1 -> W1T (f32, for k1); W2/Wo1/Wo2 -> transposed bf16 (for k2).
// 64 blocks x 256 threads.
// ---------------------------------------------------------------------------
__global__ __launch_bounds__(256) void k0_tr(const float* __restrict__ W1,
                                             const float* __restrict__ W2,
                                             const float* __restrict__ Wo1,
                                             const float* __restrict__ Wo2,
                                             float* __restrict__ W1T,
                                             u16* __restrict__ wTb) {
    __shared__ float tl[64][68];
    const int b = blockIdx.x;
    const int t = threadIdx.x;
    const int m = b >> 4, tile = b & 15;
    const float* src = (m == 0) ? W1 : (m == 1) ? W2 : (m == 2) ? Wo1 : Wo2;
    const int sr0 = (tile >> 2) * 64;
    const int sc0 = (tile & 3) * 64;
    const int rr = t >> 4;
    const int cc = (t & 15) * 4;
    #pragma unroll
    for (int it = 0; it < 4; ++it) {
        const int row = rr + 16 * it;
        float4 v = *(const float4*)&src[(sr0 + row) * HH + sc0 + cc];
        tl[row][cc + 0] = v.x;
        tl[row][cc + 1] = v.y;
        tl[row][cc + 2] = v.z;
        tl[row][cc + 3] = v.w;
    }
    __syncthreads();
    if (m == 0) {
        #pragma unroll
        for (int it = 0; it < 4; ++it) {
            const int lc = rr + 16 * it;
            float4 o;
            o.x = tl[cc + 0][lc];
            o.y = tl[cc + 1][lc];
            o.z = tl[cc + 2][lc];
            o.w = tl[cc + 3][lc];
            *(float4*)&W1T[(sc0 + lc) * HH + sr0 + cc] = o;
        }
    } else {
        u16* dst = wTb + (m - 1) * (HH * HH);
        #pragma unroll
        for (int it = 0; it < 4; ++it) {
            const int lc = rr + 16 * it;
            uint32 lo = bfr(tl[cc + 0][lc]) | (bfr(tl[cc + 1][lc]) << 16);
            uint32 hi = bfr(tl[cc + 2][lc]) | (bfr(tl[cc + 3][lc]) << 16);
            uint32* p = (uint32*)&dst[(sc0 + lc) * HH + sr0 + cc];
            p[0] = lo;
            p[1] = hi;
        }
    }
}

// ---------------------------------------------------------------------------
// k1: pa = x@Wa^T, pbb = x@Wb^T + b1 from W1T (f32, coalesced, rotated).
// 256 blocks x 256 threads.
// ---------------------------------------------------------------------------
__global__ __launch_bounds__(256) void k1_papb(const float* __restrict__ x,
                                               const float* __restrict__ W1T,
                                               const float* __restrict__ b1,
                                               float* __restrict__ pa,
                                               float* __restrict__ pbb) {
    __shared__ float xs[2][DD];
    const int b = blockIdx.x;
    const int t = threadIdx.x;
    const int i0 = b * 2;
    if (t < 64) {
        const int f = t * 4;
        *(float4*)&xs[f >> 7][f & 127] = *(const float4*)&x[i0 * DD + f];
    }
    __syncthreads();
    const float* wt = W1T + t;
    const int crot = (b * 8) & 127;
    float pe0 = 0.f, po0 = 0.f, pe1 = 0.f, po1 = 0.f;
    float qe0 = 0.f, qo0 = 0.f, qe1 = 0.f, qo1 = 0.f;
    #pragma unroll 2
    for (int cc0 = 0; cc0 < 128; cc0 += 8) {
        const int c = (cc0 + crot) & 127;
        float w0 = wt[(c + 0) * HH], w1 = wt[(c + 1) * HH];
        float w2 = wt[(c + 2) * HH], w3 = wt[(c + 3) * HH];
        float w4 = wt[(c + 4) * HH], w5 = wt[(c + 5) * HH];
        float w6 = wt[(c + 6) * HH], w7 = wt[(c + 7) * HH];
        float v0 = wt[(128 + c + 0) * HH], v1 = wt[(128 + c + 1) * HH];
        float v2 = wt[(128 + c + 2) * HH], v3 = wt[(128 + c + 3) * HH];
        float v4 = wt[(128 + c + 4) * HH], v5 = wt[(128 + c + 5) * HH];
        float v6 = wt[(128 + c + 6) * HH], v7 = wt[(128 + c + 7) * HH];
        float4 x0a = *(const float4*)&xs[0][c];
        float4 x0b = *(const float4*)&xs[0][c + 4];
        float4 x1a = *(const float4*)&xs[1][c];
        float4 x1b = *(const float4*)&xs[1][c + 4];
        pe0 += w0 * x0a.x + w1 * x0a.y + w2 * x0a.z + w3 * x0a.w;
        po0 += w4 * x0b.x + w5 * x0b.y + w6 * x0b.z + w7 * x0b.w;
        pe1 += w0 * x1a.x + w1 * x1a.y + w2 * x1a.z + w3 * x1a.w;
        po1 += w4 * x1b.x + w5 * x1b.y + w6 * x1b.z + w7 * x1b.w;
        qe0 += v0 * x0a.x + v1 * x0a.y + v2 * x0a.z + v3 * x0a.w;
        qo0 += v4 * x0b.x + v5 * x0b.y + v6 * x0b.z + v7 * x0b.w;
        qe1 += v0 * x1a.x + v1 * x1a.y + v2 * x1a.z + v3 * x1a.w;
        qo1 += v4 * x1b.x + v5 * x1b.y + v6 * x1b.z + v7 * x1b.w;
    }
    const float bb = b1[t];
    pa[i0 * HH + t] = pe0 + po0;
    pa[(i0 + 1) * HH + t] = pe1 + po1;
    pbb[i0 * HH + t] = qe0 + qo0 + bb;
    pbb[(i0 + 1) * HH + t] = qe1 + qo1 + bb;
}

// ---------------------------------------------------------------------------
// k2: fused T + rowsum + 3 stage GEMMs. f32 pa float4 T-phase, bf16 stage
// weights. 256 blocks x 1024 threads, 2 rows/block. (Measured best: R14.)
// ---------------------------------------------------------------------------
__global__ __launch_bounds__(1024) void k2_rest(const float* __restrict__ adj,
                                                const float* __restrict__ pa,
                                                const float* __restrict__ pbb,
                                                const u16* __restrict__ wTb,
                                                const float* __restrict__ b2,
                                                const float* __restrict__ bo1,
                                                const float* __restrict__ bo2,
                                                float* __restrict__ out) {
    __shared__ float adjs[2][NN];
    __shared__ float4 pbbs4[2][64];
    __shared__ float ts[2][HH];
    __shared__ float buf1[2][HH];
    __shared__ float buf2[2][HH];
    __shared__ float redbuf[8192];
    __shared__ float rsum_s[2];

    const int b = blockIdx.x;
    const int t = threadIdx.x;
    const int i0 = b * 2;

    if (t < 256) {
        const int f = t * 4;
        *(float4*)&adjs[f >> 9][f & 511] = *(const float4*)&adj[(i0 + (f >> 9)) * NN + (f & 511)];
    } else if (t < 384) {
        const int u = t - 256;
        const int r = u >> 6, q = u & 63;
        pbbs4[r][q] = *(const float4*)&pbb[(i0 + r) * HH + q * 4];
    }
    __syncthreads();

    if (t < 128) {
        const int r = t >> 6, l = t & 63;
        float s = 0.f;
        #pragma unroll
        for (int m = 0; m < 8; ++m) s += adjs[r][l + 64 * m];
        #pragma unroll
        for (int off = 32; off > 0; off >>= 1) s += __shfl_down(s, off, 64);
        if (l == 0) rsum_s[r] = s;
    }

    // ---- T phase: hq = t&63 (h-quad), js = t>>6 (16-way j split) ----
    {
        const int hq = t & 63;
        const int js = t >> 6;
        const float4 pb0 = pbbs4[0][hq];
        const float4 pb1 = pbbs4[1][hq];
        float4 ac0 = {0.f, 0.f, 0.f, 0.f};
        float4 ac1 = {0.f, 0.f, 0.f, 0.f};
        #pragma unroll 4
        for (int jj = 0; jj < 32; ++jj) {
            const int j = js * 32 + ((jj + b) & 31);
            float4 p = *(const float4*)&pa[j * HH + hq * 4];
            const float a0 = adjs[0][j];
            const float a1 = adjs[1][j];
            ac0.x += a0 * fmaxf(p.x + pb0.x, 0.f);
            ac0.y += a0 * fmaxf(p.y + pb0.y, 0.f);
            ac0.z += a0 * fmaxf(p.z + pb0.z, 0.f);
            ac0.w += a0 * fmaxf(p.w + pb0.w, 0.f);
            ac1.x += a1 * fmaxf(p.x + pb1.x, 0.f);
            ac1.y += a1 * fmaxf(p.y + pb1.y, 0.f);
            ac1.z += a1 * fmaxf(p.z + pb1.z, 0.f);
            ac1.w += a1 * fmaxf(p.w + pb1.w, 0.f);
        }
        *(float4*)&redbuf[(js * 2 + 0) * 256 + hq * 4] = ac0;
        *(float4*)&redbuf[(js * 2 + 1) * 256 + hq * 4] = ac1;
        __syncthreads();
        if (t < 512) {
            const int r = t >> 8, h = t & 255;
            float s = 0.f;
            #pragma unroll
            for (int q = 0; q < 16; ++q) s += redbuf[(q * 2 + r) * 256 + h];
            ts[r][h] = s;
        }
    }
    __syncthreads();

    const int kq = t & 63;
    const int hp = t >> 6;
    const uint32* W2U  = (const uint32*)wTb;
    const uint32* Wo1U = W2U + (HH * HH) / 2;
    const uint32* Wo2U = W2U + (HH * HH);

    // stage 1: pred = (ts @ W2T + b2*rowsum)/N -> buf1
    {
        float4 a0 = {0.f, 0.f, 0.f, 0.f};
        float4 a1 = {0.f, 0.f, 0.f, 0.f};
        #pragma unroll 4
        for (int hh = 0; hh < 16; ++hh) {
            const int h = hp * 16 + hh;
            uint32 wx = W2U[h * 128 + kq * 2];
            uint32 wy = W2U[h * 128 + kq * 2 + 1];
            float w0 = __uint_as_float(wx << 16);
            float w1 = __uint_as_float(wx & 0xffff0000u);
            float w2 = __uint_as_float(wy << 16);
            float w3 = __uint_as_float(wy & 0xffff0000u);
            const float v0 = ts[0][h];
            const float v1 = ts[1][h];
            a0.x += w0 * v0; a0.y += w1 * v0; a0.z += w2 * v0; a0.w += w3 * v0;
            a1.x += w0 * v1; a1.y += w1 * v1; a1.z += w2 * v1; a1.w += w3 * v1;
        }
        *(float4*)&redbuf[(hp * 2 + 0) * 256 + kq * 4] = a0;
        *(float4*)&redbuf[(hp * 2 + 1) * 256 + kq * 4] = a1;
        __syncthreads();
        if (t < 512) {
            const int r = t >> 8, k = t & 255;
            float s = 0.f;
            #pragma unroll
            for (int p = 0; p < 16; ++p) s += redbuf[(p * 2 + r) * 256 + k];
            buf1[r][k] = (s + b2[k] * rsum_s[r]) * (1.0f / (float)NN);
        }
    }
    __syncthreads();

    // stage 2: h2 = relu(pred @ Wo1T + bo1) -> buf2
    {
        float4 a0 = {0.f, 0.f, 0.f, 0.f};
        float4 a1 = {0.f, 0.f, 0.f, 0.f};
        #pragma unroll 4
        for (int hh = 0; hh < 16; ++hh) {
            const int h = hp * 16 + hh;
            uint32 wx = Wo1U[h * 128 + kq * 2];
            uint32 wy = Wo1U[h * 128 + kq * 2 + 1];
            float w0 = __uint_as_float(wx << 16);
            float w1 = __uint_as_float(wx & 0xffff0000u);
            float w2 = __uint_as_float(wy << 16);
            float w3 = __uint_as_float(wy & 0xffff0000u);
            const float v0 = buf1[0][h];
            const float v1 = buf1[1][h];
            a0.x += w0 * v0; a0.y += w1 * v0; a0.z += w2 * v0; a0.w += w3 * v0;
            a1.x += w0 * v1; a1.y += w1 * v1; a1.z += w2 * v1; a1.w += w3 * v1;
        }
        *(float4*)&redbuf[(hp * 2 + 0) * 256 + kq * 4] = a0;
        *(float4*)&redbuf[(hp * 2 + 1) * 256 + kq * 4] = a1;
        __syncthreads();
        if (t < 512) {
            const int r = t >> 8, k = t & 255;
            float s = 0.f;
            #pragma unroll
            for (int p = 0; p < 16; ++p) s += redbuf[(p * 2 + r) * 256 + k];
            buf2[r][k] = fmaxf(s + bo1[k], 0.f);
        }
    }
    __syncthreads();

    // stage 3: out = h2 @ Wo2T + bo2
    {
        float4 a0 = {0.f, 0.f, 0.f, 0.f};
        float4 a1 = {0.f, 0.f, 0.f, 0.f};
        #pragma unroll 4
        for (int hh = 0; hh < 16; ++hh) {
            const int h = hp * 16 + hh;
            uint32 wx = Wo2U[h * 128 + kq * 2];
            uint32 wy = Wo2U[h * 128 + kq * 2 + 1];
            float w0 = __uint_as_float(wx << 16);
            float w1 = __uint_as_float(wx & 0xffff0000u);
            float w2 = __uint_as_float(wy << 16);
            float w3 = __uint_as_float(wy & 0xffff0000u);
            const float v0 = buf2[0][h];
            const float v1 = buf2[1][h];
            a0.x += w0 * v0; a0.y += w1 * v0; a0.z += w2 * v0; a0.w += w3 * v0;
            a1.x += w0 * v1; a1.y += w1 * v1; a1.z += w2 * v1; a1.w += w3 * v1;
        }
        *(float4*)&redbuf[(hp * 2 + 0) * 256 + kq * 4] = a0;
        *(float4*)&redbuf[(hp * 2 + 1) * 256 + kq * 4] = a1;
        __syncthreads();
        if (t < 512) {
            const int r = t >> 8, k = t & 255;
            float s = 0.f;
            #pragma unroll
            for (int p = 0; p < 16; ++p) s += redbuf[(p * 2 + r) * 256 + k];
            out[(i0 + r) * HH + k] = s + bo2[k];
        }
    }
}

extern "C" void kernel_launch(void* const* d_in, const int* in_sizes, int n_in,
                              void* d_out, int out_size, void* d_ws, size_t ws_size,
                              hipStream_t stream) {
    const float* x   = (const float*)d_in[0];
    const float* adj = (const float*)d_in[1];
    const float* W1  = (const float*)d_in[2];
    const float* b1  = (const float*)d_in[3];
    const float* W2  = (const float*)d_in[4];
    const float* b2  = (const float*)d_in[5];
    const float* Wo1 = (const float*)d_in[6];
    const float* bo1 = (const float*)d_in[7];
    const float* Wo2 = (const float*)d_in[8];
    const float* bo2 = (const float*)d_in[9];
    float* out = (float*)d_out;
    float* ws  = (float*)d_ws;

    // Disjoint float-slot regions (audited):
    //   W1T : [0,       65536)   f32 256x256
    //   wTb : [65536,  163840)   3 x 256x256 bf16 = 98304 float slots
    //   pa  : [163840, 294912)   f32 512x256
    //   pbb : [294912, 425984)   f32 512x256
    float* W1T = ws;
    u16*   wTb = (u16*)(ws + 65536);
    float* pa  = ws + 163840;
    float* pbb = ws + 294912;

    k0_tr<<<64, 256, 0, stream>>>(W1, W2, Wo1, Wo2, W1T, wTb);
    k1_papb<<<256, 256, 0, stream>>>(x, W1T, b1, pa, pbb);
    k2_rest<<<256, 1024, 0, stream>>>(adj, pa, pbb, wTb, b2, bo1, bo2, out);
}